// Round 31
// baseline (742.082 us; speedup 1.0000x reference)
//
#include <hip/hip_runtime.h>
#include <math.h>

#define NAO    384
#define NELEC  96
#define NFIELD 512
#define NTS    10
#define NN     (NAO*NAO)     // 147456
#define LWIDX  (NAO*NELEC)   // float index 36864 = lw slot

// d_out: 36865 float32 = real(w) row-major (384,96) + lw scalar.
// ws layout (float units):
//   [0, NN/2)        Mh bf16 (NN ushorts)
//   [NN/2, NN)       Mf bf16
//   [NN, 6NN)        F bf16 (10 * NN ushorts)
//   [6NN, 6NN+NN/2)  hmf bf16
//   [6NN+NN/2, +96)  lognorm fp32

__device__ __forceinline__ unsigned short f2bf(float x) {  // bf16 RNE
  unsigned u = __float_as_uint(x);
  return (unsigned short)((u + 0x7FFFu + ((u >> 16) & 1u)) >> 16);
}
__device__ __forceinline__ float bf2f(unsigned short b) {
  return __uint_as_float(((unsigned)b) << 16);
}
__device__ __forceinline__ float bflo(unsigned u) {
  return __uint_as_float(u << 16);
}
__device__ __forceinline__ float bfhi(unsigned u) {
  return __uint_as_float(u & 0xFFFF0000u);
}

// ---- hmf fp32 -> bf16 (one-shot, tiny) -------------------------------------
__global__ __launch_bounds__(384) void rV_cvt(const float* __restrict__ hmf,
                                              unsigned short* __restrict__ hb) {
  const int i = blockIdx.x * 384 + threadIdx.x;
  float4 v = ((const float4*)hmf)[i];
  ushort4 o;
  o.x = f2bf(v.x); o.y = f2bf(v.y); o.z = f2bf(v.z); o.w = f2bf(v.w);
  ((ushort4*)hb)[i] = o;
}

// ---- build 4 cols of Taylor6(sc*hmf) from bf16 hmf; store bf16 col-major ---
__device__ void rV_expm_cols(const unsigned short* __restrict__ hmfb, float sc,
                             int c0, unsigned short* __restrict__ Mdst, float* s) {
  float* xs = s;            // [4][384]
  float* part = s + 1536;   // [ks(4)][c(4)][384]
  const int t = threadIdx.x, g = t % 96, ks = t / 96;
#pragma unroll
  for (int c = 0; c < 4; ++c) xs[c * 384 + t] = (t == c0 + c) ? 1.f : 0.f;
  __syncthreads();
  const ushort4* __restrict__ A4 = (const ushort4*)hmfb;
  for (int i = 6; i >= 1; --i) {
    float4 acc[4];
#pragma unroll
    for (int c = 0; c < 4; ++c) acc[c] = make_float4(0.f, 0.f, 0.f, 0.f);
    const int kb = ks * 96;
#pragma unroll 2
    for (int kk = 0; kk < 96; kk += 4) {
      float xv[4][4];
#pragma unroll
      for (int c = 0; c < 4; ++c) {
        float4 x4 = *(const float4*)&xs[c * 384 + kb + kk];
        xv[c][0] = x4.x; xv[c][1] = x4.y; xv[c][2] = x4.z; xv[c][3] = x4.w;
      }
#pragma unroll
      for (int u = 0; u < 4; ++u) {
        ushort4 b = A4[(size_t)(kb + kk + u) * 96 + g];
        float ax = bf2f(b.x), ay = bf2f(b.y), az = bf2f(b.z), aw = bf2f(b.w);
#pragma unroll
        for (int c = 0; c < 4; ++c) {
          acc[c].x = fmaf(ax, xv[c][u], acc[c].x);
          acc[c].y = fmaf(ay, xv[c][u], acc[c].y);
          acc[c].z = fmaf(az, xv[c][u], acc[c].z);
          acc[c].w = fmaf(aw, xv[c][u], acc[c].w);
        }
      }
    }
    __syncthreads();
#pragma unroll
    for (int c = 0; c < 4; ++c) *(float4*)&part[(ks * 4 + c) * 384 + 4 * g] = acc[c];
    __syncthreads();
    const float s_i = sc / (float)i;
    float nx[4];
#pragma unroll
    for (int c = 0; c < 4; ++c)
      nx[c] = ((t == c0 + c) ? 1.f : 0.f) +
              s_i * (part[(0 + c) * 384 + t] + part[(4 + c) * 384 + t] +
                     part[(8 + c) * 384 + t] + part[(12 + c) * 384 + t]);
    __syncthreads();
#pragma unroll
    for (int c = 0; c < 4; ++c) xs[c * 384 + t] = nx[c];
    __syncthreads();
  }
#pragma unroll
  for (int c = 0; c < 4; ++c)
    Mdst[(size_t)(c0 + c) * NAO + t] = f2bf(xs[c * 384 + t]);
}

__global__ __launch_bounds__(384) void rV_expm(const unsigned short* __restrict__ hmfb,
                                               const float* __restrict__ ts_v,
                                               unsigned short* __restrict__ mh,
                                               unsigned short* __restrict__ mf) {
  __shared__ __align__(16) float smem[7680];
  const int b = blockIdx.x;              // 0..191
  const float dt = ts_v[0];
  if (b < 96) rV_expm_cols(hmfb, -0.5f * dt, 4 * b, mh, smem);
  else        rV_expm_cols(hmfb, -dt, 4 * (b - 96), mf, smem);
}

// ---- F_t = sum_k fields[t,k]*vhs[k]; 288 blocks x 128 thr, unroll 8, bf16 out
__global__ __launch_bounds__(128) void rV_buildF(const float* __restrict__ vhs,
                                                 const float* __restrict__ fields,
                                                 unsigned short* __restrict__ Fout) {
  __shared__ __align__(16) float lf[NFIELD * 12];  // [k][t] padded
  for (int idx = threadIdx.x; idx < NTS * NFIELD; idx += 128) {
    int tt = idx / NFIELD, k = idx - tt * NFIELD;
    lf[k * 12 + tt] = fields[idx];
  }
  __syncthreads();
  const int e4 = blockIdx.x * 128 + threadIdx.x;   // 288*128 = 36864 = NN/4
  const float4* __restrict__ v4 = (const float4*)vhs;
  float4 acc[NTS];
#pragma unroll
  for (int tt = 0; tt < NTS; ++tt) acc[tt] = make_float4(0.f, 0.f, 0.f, 0.f);
#pragma unroll 8
  for (int k = 0; k < NFIELD; ++k) {
    float4 v = v4[(size_t)k * (NN / 4) + e4];
#pragma unroll
    for (int tt = 0; tt < NTS; ++tt) {
      float f = lf[k * 12 + tt];
      acc[tt].x = fmaf(f, v.x, acc[tt].x);
      acc[tt].y = fmaf(f, v.y, acc[tt].y);
      acc[tt].z = fmaf(f, v.z, acc[tt].z);
      acc[tt].w = fmaf(f, v.w, acc[tt].w);
    }
  }
  ushort4* F4 = (ushort4*)Fout;
#pragma unroll
  for (int tt = 0; tt < NTS; ++tt) {
    ushort4 o;
    o.x = f2bf(acc[tt].x); o.y = f2bf(acc[tt].y);
    o.z = f2bf(acc[tt].z); o.w = f2bf(acc[tt].w);
    F4[(size_t)tt * (NN / 4) + e4] = o;
  }
}

// ---- y = M x (bf16 M, fp32 x); 12 waves = 6 row-pairs x 2 K-halves ---------
// wave: 8 rowgroups(8 rows) x 8 K-slices(24 cols); butterfly-reduce over slices
// pRI layout: [h][RI][384] -> pRI[h*768 + ri*384 + row]
__device__ __forceinline__ void rV_mv(const unsigned short* __restrict__ M,
                                      const float* tr, const float* ti,
                                      float* pRI,
                                      int r0, int kb, int sl, int t,
                                      int h,
                                      float& sR, float& sI) {
  float aR[8], aI[8];
#pragma unroll
  for (int r = 0; r < 8; ++r) { aR[r] = 0.f; aI[r] = 0.f; }
  const unsigned short* Mg = M + (size_t)kb * 384 + r0;
#pragma unroll 8
  for (int c = 0; c < 24; ++c) {
    uint4 m = *(const uint4*)(Mg + (size_t)c * 384);   // 8 bf16 rows, 16 B
    const float r0v = tr[kb + c];                      // LDS broadcast read
    const float i0v = ti[kb + c];
    float a0 = bflo(m.x), a1 = bfhi(m.x);
    float a2 = bflo(m.y), a3 = bfhi(m.y);
    float a4 = bflo(m.z), a5 = bfhi(m.z);
    float a6 = bflo(m.w), a7 = bfhi(m.w);
    aR[0] = fmaf(a0, r0v, aR[0]); aI[0] = fmaf(a0, i0v, aI[0]);
    aR[1] = fmaf(a1, r0v, aR[1]); aI[1] = fmaf(a1, i0v, aI[1]);
    aR[2] = fmaf(a2, r0v, aR[2]); aI[2] = fmaf(a2, i0v, aI[2]);
    aR[3] = fmaf(a3, r0v, aR[3]); aI[3] = fmaf(a3, i0v, aI[3]);
    aR[4] = fmaf(a4, r0v, aR[4]); aI[4] = fmaf(a4, i0v, aI[4]);
    aR[5] = fmaf(a5, r0v, aR[5]); aI[5] = fmaf(a5, i0v, aI[5]);
    aR[6] = fmaf(a6, r0v, aR[6]); aI[6] = fmaf(a6, i0v, aI[6]);
    aR[7] = fmaf(a7, r0v, aR[7]); aI[7] = fmaf(a7, i0v, aI[7]);
  }
  // butterfly reduce over the 8 K-slices (lane bits 0..2)
#pragma unroll
  for (int off = 1; off < 8; off <<= 1) {
#pragma unroll
    for (int r = 0; r < 8; ++r) {
      aR[r] += __shfl_xor(aR[r], off, 64);
      aI[r] += __shfl_xor(aI[r], off, 64);
    }
  }
  if (sl == 0) {                          // 8 lanes/wave write 8 rows each
    float* bR = &pRI[h * 768 + r0];
    float* bI = &pRI[h * 768 + 384 + r0];
    *(float4*)&bR[0] = make_float4(aR[0], aR[1], aR[2], aR[3]);
    *(float4*)&bR[4] = make_float4(aR[4], aR[5], aR[6], aR[7]);
    *(float4*)&bI[0] = make_float4(aI[0], aI[1], aI[2], aI[3]);
    *(float4*)&bI[4] = make_float4(aI[4], aI[5], aI[6], aI[7]);
  }
  __syncthreads();                        // partial writes -> combine reads
  if (t < 384) {
    sR = pRI[t] + pRI[768 + t];           // h=0 + h=1
    sI = pRI[384 + t] + pRI[1152 + t];
  } else { sR = 0.f; sI = 0.f; }
}

// ---- full 10-step propagation of column j; 96 blocks x 768 threads ---------
__global__ __launch_bounds__(768) void rV_prop(const float* __restrict__ wfn,
                                               const float* __restrict__ ts_v,
                                               const unsigned short* __restrict__ mh,
                                               const unsigned short* __restrict__ mf,
                                               const unsigned short* __restrict__ Fb,
                                               float* __restrict__ out,
                                               float* __restrict__ lognorm) {
  __shared__ __align__(16) float smem[2316];
  float* tr = smem; float* ti = smem + 384;
  float* pRI = smem + 768;         // [2][2][384] = 1536
  float* red = smem + 2304;        // 12
  const int j = blockIdx.x;
  const int t = threadIdx.x;
  const int wave = t >> 6, lane = t & 63;
  const int p = wave >> 1, h = wave & 1;
  const int rg = lane >> 3, sl = lane & 7;
  const int r0 = (p << 6) + (rg << 3);    // row base (8 rows)
  const int kb = h * 192 + sl * 24;       // col base (24 cols)
  if (t < 384) { tr[t] = wfn[t * NELEC + j]; ti[t] = 0.f; }
  float lacc = 0.f;
  __syncthreads();
  for (int st = 0; st < NTS; ++st) {
    const unsigned short* M = (st == 0) ? mh : mf;
    float sR, sI;
    rV_mv(M, tr, ti, pRI, r0, kb, sl, t, h, sR, sI);   // one-body step
    if (t < 384) { tr[t] = sR; ti[t] = sI; }
    float o_r = sR, o_i = sI;                           // Taylor accumulator
    __syncthreads();
    const unsigned short* F = Fb + (size_t)st * NN;
    const float sdt = sqrtf(ts_v[st]);                  // V = i*sdt*F
    for (int i = 1; i <= 6; ++i) {
      rV_mv(F, tr, ti, pRI, r0, kb, sl, t, h, sR, sI);  // sR=F@re, sI=F@im
      const float f = sdt / (float)i;
      const float nr = -f * sI, ni = f * sR;
      o_r += nr; o_i += ni;
      if (t < 384) { tr[t] = nr; ti[t] = ni; }
      __syncthreads();
    }
    float v = (t < 384) ? (o_r * o_r + o_i * o_i) : 0.f;
#pragma unroll
    for (int o = 1; o < 64; o <<= 1) v += __shfl_xor(v, o, 64);
    if (lane == 0) red[wave] = v;
    __syncthreads();
    float tot = 0.f;
#pragma unroll
    for (int s2 = 0; s2 < 12; ++s2) tot += red[s2];
    const float nrm = sqrtf(tot);
    const float inv = 1.f / nrm;
    o_r *= inv; o_i *= inv;
    lacc += logf(nrm);
    if (t < 384) { tr[t] = o_r; ti[t] = o_i; }
    __syncthreads();
  }
  float sR, sI;
  rV_mv(mh, tr, ti, pRI, r0, kb, sl, t, h, sR, sI);     // final half step
  // imag(lw)==0 exactly -> phase factor is 1; harness reads real(w) only.
  if (t < 384) out[t * NELEC + j] = sR;
  if (t == 0) lognorm[j] = lacc;
}

// ---- lw writer: float32 at index 36864
__global__ void rV_fin(const float* __restrict__ lognorm,
                       const float* __restrict__ enuc,
                       float* __restrict__ out) {
  __shared__ float red[2];
  const int t = threadIdx.x;             // 128 threads
  float v = (t < NELEC) ? lognorm[t] : 0.f;
#pragma unroll
  for (int o = 1; o < 64; o <<= 1) v += __shfl_xor(v, o, 64);
  if ((t & 63) == 0) red[t >> 6] = v;
  __syncthreads();
  if (t == 0) out[LWIDX] = enuc[0] + red[0] + red[1];
}

extern "C" void kernel_launch(void* const* d_in, const int* in_sizes, int n_in,
                              void* d_out, int out_size, void* d_ws, size_t ws_size,
                              hipStream_t stream) {
  const float* wfn    = (const float*)d_in[0];
  const float* fields = (const float*)d_in[1];
  const float* hmf    = (const float*)d_in[2];
  const float* vhs    = (const float*)d_in[3];
  const float* ts_v   = (const float*)d_in[4];
  const float* enuc   = (const float*)d_in[5];
  float* out = (float*)d_out;          // 36865 float32: real(w) + lw
  float* ws  = (float*)d_ws;
  unsigned short* mh    = (unsigned short*)ws;                 // NN bf16
  unsigned short* mf    = (unsigned short*)(ws + NN / 2);      // NN bf16
  unsigned short* Fb    = (unsigned short*)(ws + NN);          // 10*NN bf16
  unsigned short* hmfb  = (unsigned short*)(ws + 6 * NN);      // NN bf16
  float* lognorm        = ws + 6 * NN + NN / 2;                // 96 fp32

  rV_cvt   <<< 96, 384, 0, stream>>>(hmf, hmfb);
  rV_expm  <<<192, 384, 0, stream>>>(hmfb, ts_v, mh, mf);
  rV_buildF<<<288, 128, 0, stream>>>(vhs, fields, Fb);
  rV_prop  <<< 96, 768, 0, stream>>>(wfn, ts_v, mh, mf, Fb, out, lognorm);
  rV_fin   <<<  1, 128, 0, stream>>>(lognorm, enuc, out);
}

// Round 32
// 361.737 us; speedup vs baseline: 2.0514x; 2.0514x over previous
//
#include <hip/hip_runtime.h>
#include <math.h>

#define NAO    384
#define NELEC  96
#define NFIELD 512
#define NTS    10
#define NN     (NAO*NAO)     // 147456
#define LWIDX  (NAO*NELEC)   // float index 36864 = lw slot

// d_out: 36865 float32 = real(w) row-major (384,96) + lw scalar.
// ws layout (float units):
//   [0, NN/2)        Mh bf16 (NN ushorts)
//   [NN/2, NN)       Mf bf16
//   [NN, 6NN)        F bf16 (10 * NN ushorts)
//   [6NN, 6NN+NN/2)  hmf bf16
//   [6NN+NN/2, +96)  lognorm fp32

__device__ __forceinline__ unsigned short f2bf(float x) {  // bf16 RNE
  unsigned u = __float_as_uint(x);
  return (unsigned short)((u + 0x7FFFu + ((u >> 16) & 1u)) >> 16);
}
__device__ __forceinline__ float bf2f(unsigned short b) {
  return __uint_as_float(((unsigned)b) << 16);
}
__device__ __forceinline__ float bflo(unsigned u) {
  return __uint_as_float(u << 16);
}
__device__ __forceinline__ float bfhi(unsigned u) {
  return __uint_as_float(u & 0xFFFF0000u);
}

// ---- hmf fp32 -> bf16 (one-shot, tiny) -------------------------------------
__global__ __launch_bounds__(384) void rW_cvt(const float* __restrict__ hmf,
                                              unsigned short* __restrict__ hb) {
  const int i = blockIdx.x * 384 + threadIdx.x;
  float4 v = ((const float4*)hmf)[i];
  ushort4 o;
  o.x = f2bf(v.x); o.y = f2bf(v.y); o.z = f2bf(v.z); o.w = f2bf(v.w);
  ((ushort4*)hb)[i] = o;
}

// ---- build 4 cols of Taylor6(sc*hmf) from bf16 hmf; store bf16 col-major ---
__device__ void rW_expm_cols(const unsigned short* __restrict__ hmfb, float sc,
                             int c0, unsigned short* __restrict__ Mdst, float* s) {
  float* xs = s;            // [4][384]
  float* part = s + 1536;   // [ks(4)][c(4)][384]
  const int t = threadIdx.x, g = t % 96, ks = t / 96;
#pragma unroll
  for (int c = 0; c < 4; ++c) xs[c * 384 + t] = (t == c0 + c) ? 1.f : 0.f;
  __syncthreads();
  const ushort4* __restrict__ A4 = (const ushort4*)hmfb;
  for (int i = 6; i >= 1; --i) {
    float4 acc[4];
#pragma unroll
    for (int c = 0; c < 4; ++c) acc[c] = make_float4(0.f, 0.f, 0.f, 0.f);
    const int kb = ks * 96;
#pragma unroll 2
    for (int kk = 0; kk < 96; kk += 4) {
      float xv[4][4];
#pragma unroll
      for (int c = 0; c < 4; ++c) {
        float4 x4 = *(const float4*)&xs[c * 384 + kb + kk];
        xv[c][0] = x4.x; xv[c][1] = x4.y; xv[c][2] = x4.z; xv[c][3] = x4.w;
      }
#pragma unroll
      for (int u = 0; u < 4; ++u) {
        ushort4 b = A4[(size_t)(kb + kk + u) * 96 + g];
        float ax = bf2f(b.x), ay = bf2f(b.y), az = bf2f(b.z), aw = bf2f(b.w);
#pragma unroll
        for (int c = 0; c < 4; ++c) {
          acc[c].x = fmaf(ax, xv[c][u], acc[c].x);
          acc[c].y = fmaf(ay, xv[c][u], acc[c].y);
          acc[c].z = fmaf(az, xv[c][u], acc[c].z);
          acc[c].w = fmaf(aw, xv[c][u], acc[c].w);
        }
      }
    }
    __syncthreads();
#pragma unroll
    for (int c = 0; c < 4; ++c) *(float4*)&part[(ks * 4 + c) * 384 + 4 * g] = acc[c];
    __syncthreads();
    const float s_i = sc / (float)i;
    float nx[4];
#pragma unroll
    for (int c = 0; c < 4; ++c)
      nx[c] = ((t == c0 + c) ? 1.f : 0.f) +
              s_i * (part[(0 + c) * 384 + t] + part[(4 + c) * 384 + t] +
                     part[(8 + c) * 384 + t] + part[(12 + c) * 384 + t]);
    __syncthreads();
#pragma unroll
    for (int c = 0; c < 4; ++c) xs[c * 384 + t] = nx[c];
    __syncthreads();
  }
#pragma unroll
  for (int c = 0; c < 4; ++c)
    Mdst[(size_t)(c0 + c) * NAO + t] = f2bf(xs[c * 384 + t]);
}

__global__ __launch_bounds__(384) void rW_expm(const unsigned short* __restrict__ hmfb,
                                               const float* __restrict__ ts_v,
                                               unsigned short* __restrict__ mh,
                                               unsigned short* __restrict__ mf) {
  __shared__ __align__(16) float smem[7680];
  const int b = blockIdx.x;              // 0..191
  const float dt = ts_v[0];
  if (b < 96) rW_expm_cols(hmfb, -0.5f * dt, 4 * b, mh, smem);
  else        rW_expm_cols(hmfb, -dt, 4 * (b - 96), mf, smem);
}

// ---- F_t = sum_k fields[t,k]*vhs[k]; 288 blocks x 128 thr, unroll 8, bf16 out
__global__ __launch_bounds__(128) void rW_buildF(const float* __restrict__ vhs,
                                                 const float* __restrict__ fields,
                                                 unsigned short* __restrict__ Fout) {
  __shared__ __align__(16) float lf[NFIELD * 12];  // [k][t] padded
  for (int idx = threadIdx.x; idx < NTS * NFIELD; idx += 128) {
    int tt = idx / NFIELD, k = idx - tt * NFIELD;
    lf[k * 12 + tt] = fields[idx];
  }
  __syncthreads();
  const int e4 = blockIdx.x * 128 + threadIdx.x;   // 288*128 = 36864 = NN/4
  const float4* __restrict__ v4 = (const float4*)vhs;
  float4 acc[NTS];
#pragma unroll
  for (int tt = 0; tt < NTS; ++tt) acc[tt] = make_float4(0.f, 0.f, 0.f, 0.f);
#pragma unroll 8
  for (int k = 0; k < NFIELD; ++k) {
    float4 v = v4[(size_t)k * (NN / 4) + e4];
#pragma unroll
    for (int tt = 0; tt < NTS; ++tt) {
      float f = lf[k * 12 + tt];
      acc[tt].x = fmaf(f, v.x, acc[tt].x);
      acc[tt].y = fmaf(f, v.y, acc[tt].y);
      acc[tt].z = fmaf(f, v.z, acc[tt].z);
      acc[tt].w = fmaf(f, v.w, acc[tt].w);
    }
  }
  ushort4* F4 = (ushort4*)Fout;
#pragma unroll
  for (int tt = 0; tt < NTS; ++tt) {
    ushort4 o;
    o.x = f2bf(acc[tt].x); o.y = f2bf(acc[tt].y);
    o.z = f2bf(acc[tt].z); o.w = f2bf(acc[tt].w);
    F4[(size_t)tt * (NN / 4) + e4] = o;
  }
}

// ---- y = M x (bf16 M, fp32 x); 768 thr = 48 8-row groups x 16 24-col slices
// partials in float4-interleaved layout P4[i4*17 + ks] (i4 = row/4):
//   writes hit all 32 banks (b128-inherent 8-way only); combine reads 2-way.
// ONE internal barrier (pre-write sync subsumed by caller's barrier).
__device__ __forceinline__ void rW_mv(const unsigned short* __restrict__ M,
                                      const float* tr, const float* ti,
                                      float* pP,
                                      int g, int ks, int t,
                                      float& sR, float& sI) {
  const int kb = ks * 24;
  float aR[8], aI[8];
#pragma unroll
  for (int r = 0; r < 8; ++r) { aR[r] = 0.f; aI[r] = 0.f; }
  const unsigned short* Mg = M + (size_t)kb * 384 + (g << 3);
#pragma unroll 8
  for (int c = 0; c < 24; ++c) {
    uint4 m = *(const uint4*)(Mg + (size_t)c * 384);   // 8 bf16 rows, 16 B
    const float r0 = tr[kb + c];                       // LDS broadcast read
    const float i0 = ti[kb + c];
    float a0 = bflo(m.x), a1 = bfhi(m.x);
    float a2 = bflo(m.y), a3 = bfhi(m.y);
    float a4 = bflo(m.z), a5 = bfhi(m.z);
    float a6 = bflo(m.w), a7 = bfhi(m.w);
    aR[0] = fmaf(a0, r0, aR[0]); aI[0] = fmaf(a0, i0, aI[0]);
    aR[1] = fmaf(a1, r0, aR[1]); aI[1] = fmaf(a1, i0, aI[1]);
    aR[2] = fmaf(a2, r0, aR[2]); aI[2] = fmaf(a2, i0, aI[2]);
    aR[3] = fmaf(a3, r0, aR[3]); aI[3] = fmaf(a3, i0, aI[3]);
    aR[4] = fmaf(a4, r0, aR[4]); aI[4] = fmaf(a4, i0, aI[4]);
    aR[5] = fmaf(a5, r0, aR[5]); aI[5] = fmaf(a5, i0, aI[5]);
    aR[6] = fmaf(a6, r0, aR[6]); aI[6] = fmaf(a6, i0, aI[6]);
    aR[7] = fmaf(a7, r0, aR[7]); aI[7] = fmaf(a7, i0, aI[7]);
  }
  // NOTE: no barrier here — caller's barrier (after tr/ti update) already
  // separates the previous combine-reads from these writes.
  float4* P4 = (float4*)pP;
  const int i40 = g << 1;                 // row/4 base (2 float4 rows per group)
  P4[(i40 + 0) * 17 + ks]        = make_float4(aR[0], aR[1], aR[2], aR[3]);
  P4[(i40 + 1) * 17 + ks]        = make_float4(aR[4], aR[5], aR[6], aR[7]);
  P4[1632 + (i40 + 0) * 17 + ks] = make_float4(aI[0], aI[1], aI[2], aI[3]);
  P4[1632 + (i40 + 1) * 17 + ks] = make_float4(aI[4], aI[5], aI[6], aI[7]);
  __syncthreads();                        // writes -> combine reads
  if (t < 384) {
    const int i4 = t >> 2, e = t & 3;
    const float* pf = pP;
    float r = 0.f, im = 0.f;
#pragma unroll
    for (int s2 = 0; s2 < 16; ++s2) {
      r  += pf[(i4 * 17 + s2) * 4 + e];
      im += pf[6528 + (i4 * 17 + s2) * 4 + e];
    }
    sR = r; sI = im;
  } else { sR = 0.f; sI = 0.f; }
}

// ---- full 10-step propagation of column j; 96 blocks x 768 threads ---------
__global__ __launch_bounds__(768) void rW_prop(const float* __restrict__ wfn,
                                               const float* __restrict__ ts_v,
                                               const unsigned short* __restrict__ mh,
                                               const unsigned short* __restrict__ mf,
                                               const unsigned short* __restrict__ Fb,
                                               float* __restrict__ out,
                                               float* __restrict__ lognorm) {
  __shared__ __align__(16) float smem[13836];
  float* tr = smem; float* ti = smem + 384;
  float* pP = smem + 768;          // 2*1632 float4 = 13056 floats
  float* red = smem + 13824;       // 12
  const int j = blockIdx.x;
  const int t = threadIdx.x, g = t % 48, ks = t / 48;
  if (t < 384) { tr[t] = wfn[t * NELEC + j]; ti[t] = 0.f; }
  float lacc = 0.f;
  __syncthreads();
  for (int st = 0; st < NTS; ++st) {
    const unsigned short* M = (st == 0) ? mh : mf;
    float sR, sI;
    rW_mv(M, tr, ti, pP, g, ks, t, sR, sI);            // one-body step
    if (t < 384) { tr[t] = sR; ti[t] = sI; }
    float o_r = sR, o_i = sI;                           // Taylor accumulator
    __syncthreads();
    const unsigned short* F = Fb + (size_t)st * NN;
    const float sdt = sqrtf(ts_v[st]);                  // V = i*sdt*F
    for (int i = 1; i <= 6; ++i) {
      rW_mv(F, tr, ti, pP, g, ks, t, sR, sI);           // sR=F@re, sI=F@im
      const float f = sdt / (float)i;
      const float nr = -f * sI, ni = f * sR;
      o_r += nr; o_i += ni;
      if (t < 384) { tr[t] = nr; ti[t] = ni; }
      __syncthreads();
    }
    float v = (t < 384) ? (o_r * o_r + o_i * o_i) : 0.f;
#pragma unroll
    for (int o = 1; o < 64; o <<= 1) v += __shfl_xor(v, o, 64);
    if ((t & 63) == 0) red[t >> 6] = v;
    __syncthreads();
    float tot = 0.f;
#pragma unroll
    for (int s2 = 0; s2 < 12; ++s2) tot += red[s2];
    const float nrm = sqrtf(tot);
    const float inv = 1.f / nrm;
    o_r *= inv; o_i *= inv;
    lacc += logf(nrm);
    if (t < 384) { tr[t] = o_r; ti[t] = o_i; }
    __syncthreads();
  }
  float sR, sI;
  rW_mv(mh, tr, ti, pP, g, ks, t, sR, sI);              // final half step
  // imag(lw)==0 exactly -> phase factor is 1; harness reads real(w) only.
  if (t < 384) out[t * NELEC + j] = sR;
  if (t == 0) lognorm[j] = lacc;
}

// ---- lw writer: float32 at index 36864
__global__ void rW_fin(const float* __restrict__ lognorm,
                       const float* __restrict__ enuc,
                       float* __restrict__ out) {
  __shared__ float red[2];
  const int t = threadIdx.x;             // 128 threads
  float v = (t < NELEC) ? lognorm[t] : 0.f;
#pragma unroll
  for (int o = 1; o < 64; o <<= 1) v += __shfl_xor(v, o, 64);
  if ((t & 63) == 0) red[t >> 6] = v;
  __syncthreads();
  if (t == 0) out[LWIDX] = enuc[0] + red[0] + red[1];
}

extern "C" void kernel_launch(void* const* d_in, const int* in_sizes, int n_in,
                              void* d_out, int out_size, void* d_ws, size_t ws_size,
                              hipStream_t stream) {
  const float* wfn    = (const float*)d_in[0];
  const float* fields = (const float*)d_in[1];
  const float* hmf    = (const float*)d_in[2];
  const float* vhs    = (const float*)d_in[3];
  const float* ts_v   = (const float*)d_in[4];
  const float* enuc   = (const float*)d_in[5];
  float* out = (float*)d_out;          // 36865 float32: real(w) + lw
  float* ws  = (float*)d_ws;
  unsigned short* mh    = (unsigned short*)ws;                 // NN bf16
  unsigned short* mf    = (unsigned short*)(ws + NN / 2);      // NN bf16
  unsigned short* Fb    = (unsigned short*)(ws + NN);          // 10*NN bf16
  unsigned short* hmfb  = (unsigned short*)(ws + 6 * NN);      // NN bf16
  float* lognorm        = ws + 6 * NN + NN / 2;                // 96 fp32

  rW_cvt   <<< 96, 384, 0, stream>>>(hmf, hmfb);
  rW_expm  <<<192, 384, 0, stream>>>(hmfb, ts_v, mh, mf);
  rW_buildF<<<288, 128, 0, stream>>>(vhs, fields, Fb);
  rW_prop  <<< 96, 768, 0, stream>>>(wfn, ts_v, mh, mf, Fb, out, lognorm);
  rW_fin   <<<  1, 128, 0, stream>>>(lognorm, enuc, out);
}